// Round 12
// baseline (276.767 us; speedup 1.0000x reference)
//
#include <hip/hip_runtime.h>
#include <hip/hip_fp16.h>

// ---------------------------------------------------------------------------
// GCN 2-layer forward: out = relu(A_hat @ relu(A_hat @ (X W1) + b1) W2 + b2)
// A_hat = D^-1/2 (A + I) D^-1/2.
// Normalization folded: g = dinv[row]*(X@W); agg_n = dinv[n]*(g[n]+sum g[src]).
// Gather table G in FP16.
// Pipeline (R10-R12): bin by dst>>6 -> sort_bins does per-bin LDS counting
// sort ONCE, persisting sorted u16 src lists + start offsets + dinv ->
// agg kernels just bulk-load their slice and register-accumulate gathers.
// Each bin split across 2 blocks (32 rows each) for latency hiding.
// All scatter is LDS-local; all global writes coalesced; no global atomics
// except bin-space reservation (R7/R8 lessons).
// Requires N <= 65536 (src packs into 16 bits).
// ---------------------------------------------------------------------------

#define TILE 8192      // edges per bin_kernel block (256 thr x 32)
#define BIN_CAP 2560   // per-bin record capacity (mean 2046, sd ~45 -> 11 sigma)

// ---- bin edges by dst>>6: rec = (d&63)<<16 | s ----
__global__ __launch_bounds__(256) void bin_kernel(const int* __restrict__ src,
                                                  const int* __restrict__ dst, int E,
                                                  int nbins,
                                                  int* __restrict__ binCnt,
                                                  unsigned* __restrict__ recs) {
    extern __shared__ int lds[];           // cnt[nbins] | gbase[nbins]
    int* cnt = lds;
    int* gbase = lds + nbins;
    int tid = threadIdx.x;
    for (int i = tid; i < nbins; i += 256) cnt[i] = 0;
    __syncthreads();

    int t0 = blockIdx.x * TILE;
    int tEnd = min(t0 + TILE, E);

    // pass 1: count per bin (LDS int atomics)
    for (int e = t0 + tid; e < tEnd; e += 256)
        atomicAdd(&cnt[dst[e] >> 6], 1);
    __syncthreads();

    // reserve global space per bin
    for (int i = tid; i < nbins; i += 256) {
        int c = cnt[i];
        gbase[i] = (c > 0) ? atomicAdd(&binCnt[i], c) : 0;
        cnt[i] = 0;                        // reuse as local cursor
    }
    __syncthreads();

    // pass 2: place records (runs within a bin are consecutive global slots)
    for (int e = t0 + tid; e < tEnd; e += 256) {
        int d = dst[e];
        int s = src[e];
        int b = d >> 6;
        int r = atomicAdd(&cnt[b], 1);
        int g = gbase[b] + r;
        if (g < BIN_CAP)
            recs[(size_t)b * BIN_CAP + g] = ((unsigned)(d & 63) << 16) | (unsigned)s;
    }
}

// ---- per-bin counting sort (once): sorted u16 lists + starts + dinv ----
__global__ __launch_bounds__(256) void sort_bins(const unsigned* __restrict__ recs,
                                                 const int* __restrict__ binCnt,
                                                 unsigned short* __restrict__ sortedG,
                                                 int* __restrict__ startG,
                                                 float* __restrict__ dinv, int N) {
    __shared__ unsigned short sorted[BIN_CAP];
    __shared__ int c64[64];
    __shared__ int start[65];
    __shared__ int cursor[64];
    int b = blockIdx.x, tid = threadIdx.x;
    int lane = tid & 63, wave = tid >> 6;

    if (tid < 64) c64[tid] = 0;
    __syncthreads();
    int cnt = min(binCnt[b], BIN_CAP);
    const unsigned* bin = recs + (size_t)b * BIN_CAP;

    // count
    for (int i = tid; i < cnt; i += 256)
        atomicAdd(&c64[bin[i] >> 16], 1);
    __syncthreads();

    // wave-0 exclusive prefix scan; persist starts + dinv
    if (wave == 0) {
        int c = c64[lane];
        int v = c;
        #pragma unroll
        for (int off = 1; off < 64; off <<= 1) {
            int t = __shfl_up(v, off);
            if (lane >= off) v += t;
        }
        start[lane] = v - c;
        cursor[lane] = v - c;
        startG[b * 65 + lane] = v - c;
        if (lane == 63) { start[64] = v; startG[b * 65 + 64] = v; }
        int n = (b << 6) + lane;
        if (n < N) dinv[n] = rsqrtf((float)(c + 1));   // +1 = self loop
    }
    __syncthreads();

    // place into LDS (LDS atomics on 64 cursors), then coalesced dump
    for (int i = tid; i < cnt; i += 256) {
        unsigned r = bin[i];
        int pos = atomicAdd(&cursor[r >> 16], 1);
        sorted[pos] = (unsigned short)(r & 0xFFFFu);
    }
    __syncthreads();
    unsigned short* sg = sortedG + (size_t)b * BIN_CAP;
    for (int i = tid; i < cnt; i += 256) sg[i] = sorted[i];
}

// ---- fp32 GEMM: Y[r,:] = half( dinv[r] * (X[r,:] @ W) ), 4x4 register tile ----
template <int COLS>
__global__ __launch_bounds__(256) void gemm_kernel(const float* __restrict__ X,
                                                   const float* __restrict__ W,
                                                   const float* __restrict__ dinv,
                                                   __half* __restrict__ Y, int N) {
    constexpr int CT = COLS / 4;
    constexpr int RT = 256 / CT;
    constexpr int ROWS = RT * 4;
    constexpr int LDT = ROWS + 4;
    __shared__ float xT[128 * LDT];        // x transposed: [k][r]

    int tid = threadIdx.x;
    int row0 = blockIdx.x * ROWS;
    int kk = tid & 127;
    for (int rr = tid >> 7; rr < ROWS; rr += 2) {
        int r = row0 + rr;
        xT[kk * LDT + rr] = (r < N) ? X[(size_t)r * 128 + kk] : 0.0f;
    }
    __syncthreads();

    int ct = tid % CT, rt = tid / CT;
    int c0 = ct * 4, r0 = rt * 4;
    float acc[4][4] = {};
    #pragma unroll 4
    for (int k = 0; k < 128; k++) {
        float4 xv = *(const float4*)&xT[k * LDT + r0];
        float4 wv = *(const float4*)&W[(size_t)k * COLS + c0];
        float xs[4] = {xv.x, xv.y, xv.z, xv.w};
        float ws[4] = {wv.x, wv.y, wv.z, wv.w};
        #pragma unroll
        for (int i = 0; i < 4; i++)
            #pragma unroll
            for (int j = 0; j < 4; j++)
                acc[i][j] = fmaf(xs[i], ws[j], acc[i][j]);
    }
    #pragma unroll
    for (int i = 0; i < 4; i++) {
        int r = row0 + r0 + i;
        if (r < N) {
            float sc = dinv[r];
            __half2 p0 = __floats2half2_rn(sc * acc[i][0], sc * acc[i][1]);
            __half2 p1 = __floats2half2_rn(sc * acc[i][2], sc * acc[i][3]);
            *(__half2*)&Y[(size_t)r * COLS + c0]     = p0;
            *(__half2*)&Y[(size_t)r * COLS + c0 + 2] = p1;
        }
    }
}

// ---- agg F=128: block (b, half) handles 32 rows of bin b; wave owns 4 rows ----
__global__ __launch_bounds__(512) void agg_128(const __half* __restrict__ G,
                                               const unsigned short* __restrict__ sortedG,
                                               const int* __restrict__ startG,
                                               const float* __restrict__ dinv,
                                               const float* __restrict__ bias,
                                               float* __restrict__ out, int N) {
    __shared__ unsigned short buf[BIN_CAP];
    __shared__ int st[33];
    int b = blockIdx.x, half = blockIdx.y;
    int tid = threadIdx.x, lane = tid & 63, wave = tid >> 6;
    int r0 = half * 32;

    if (tid < 33) st[tid] = startG[b * 65 + r0 + tid];
    __syncthreads();
    int S0 = st[0], S1 = st[32];
    const unsigned short* sg = sortedG + (size_t)b * BIN_CAP;
    for (int i = tid; i < S1 - S0; i += 512) buf[i] = sg[S0 + i];
    __syncthreads();

    float bx = bias[lane * 2], by = bias[lane * 2 + 1];
    for (int rr = 0; rr < 4; rr++) {
        int row = wave * 4 + rr;               // 0..31
        int n = (b << 6) + r0 + row;
        if (n >= N) continue;
        int jst = st[row] - S0, jen = st[row + 1] - S0;
        float2 self = __half22float2(*(const __half2*)&G[(size_t)n * 128 + lane * 2]);
        float ax = self.x, ay = self.y;
        int j = jst;
        for (; j + 8 <= jen; j += 8) {
            int s0 = buf[j],     s1 = buf[j + 1];
            int s2 = buf[j + 2], s3 = buf[j + 3];
            int s4 = buf[j + 4], s5 = buf[j + 5];
            int s6 = buf[j + 6], s7 = buf[j + 7];
            float2 v0 = __half22float2(*(const __half2*)&G[(size_t)s0 * 128 + lane * 2]);
            float2 v1 = __half22float2(*(const __half2*)&G[(size_t)s1 * 128 + lane * 2]);
            float2 v2 = __half22float2(*(const __half2*)&G[(size_t)s2 * 128 + lane * 2]);
            float2 v3 = __half22float2(*(const __half2*)&G[(size_t)s3 * 128 + lane * 2]);
            float2 v4 = __half22float2(*(const __half2*)&G[(size_t)s4 * 128 + lane * 2]);
            float2 v5 = __half22float2(*(const __half2*)&G[(size_t)s5 * 128 + lane * 2]);
            float2 v6 = __half22float2(*(const __half2*)&G[(size_t)s6 * 128 + lane * 2]);
            float2 v7 = __half22float2(*(const __half2*)&G[(size_t)s7 * 128 + lane * 2]);
            ax += ((v0.x + v1.x) + (v2.x + v3.x)) + ((v4.x + v5.x) + (v6.x + v7.x));
            ay += ((v0.y + v1.y) + (v2.y + v3.y)) + ((v4.y + v5.y) + (v6.y + v7.y));
        }
        for (; j < jen; j++) {
            int s = buf[j];
            float2 v = __half22float2(*(const __half2*)&G[(size_t)s * 128 + lane * 2]);
            ax += v.x; ay += v.y;
        }
        float di = dinv[n];
        float ox = fmaxf(fmaf(di, ax, bx), 0.0f);
        float oy = fmaxf(fmaf(di, ay, by), 0.0f);
        *(float2*)&out[(size_t)n * 128 + lane * 2] = make_float2(ox, oy);
    }
}

// ---- agg F=64: block (b, half) = 32 rows; HALF-wave (32 lanes, half2)/node ----
__global__ __launch_bounds__(512) void agg_64(const __half* __restrict__ G,
                                              const unsigned short* __restrict__ sortedG,
                                              const int* __restrict__ startG,
                                              const float* __restrict__ dinv,
                                              const float* __restrict__ bias,
                                              float* __restrict__ out, int N) {
    __shared__ unsigned short buf[BIN_CAP];
    __shared__ int st[33];
    int b = blockIdx.x, half = blockIdx.y;
    int tid = threadIdx.x, lane = tid & 63, wave = tid >> 6;
    int hl = lane & 31, side = lane >> 5;
    int r0 = half * 32;

    if (tid < 33) st[tid] = startG[b * 65 + r0 + tid];
    __syncthreads();
    int S0 = st[0], S1 = st[32];
    const unsigned short* sg = sortedG + (size_t)b * BIN_CAP;
    for (int i = tid; i < S1 - S0; i += 512) buf[i] = sg[S0 + i];
    __syncthreads();

    float bx = bias[hl * 2], by = bias[hl * 2 + 1];
    for (int pp = 0; pp < 2; pp++) {
        int row = wave * 4 + pp * 2 + side;    // 0..31
        int n = (b << 6) + r0 + row;
        bool live = (n < N);
        int jst = live ? (st[row] - S0) : 0;
        int jen = live ? (st[row + 1] - S0) : 0;
        float ax = 0.0f, ay = 0.0f;
        if (live) {
            float2 self = __half22float2(*(const __half2*)&G[(size_t)n * 64 + hl * 2]);
            ax = self.x; ay = self.y;
        }
        int j = jst;
        for (; j + 4 <= jen; j += 4) {
            int s0 = buf[j],     s1 = buf[j + 1];
            int s2 = buf[j + 2], s3 = buf[j + 3];
            float2 v0 = __half22float2(*(const __half2*)&G[(size_t)s0 * 64 + hl * 2]);
            float2 v1 = __half22float2(*(const __half2*)&G[(size_t)s1 * 64 + hl * 2]);
            float2 v2 = __half22float2(*(const __half2*)&G[(size_t)s2 * 64 + hl * 2]);
            float2 v3 = __half22float2(*(const __half2*)&G[(size_t)s3 * 64 + hl * 2]);
            ax += (v0.x + v1.x) + (v2.x + v3.x);
            ay += (v0.y + v1.y) + (v2.y + v3.y);
        }
        for (; j < jen; j++) {
            int s = buf[j];
            float2 v = __half22float2(*(const __half2*)&G[(size_t)s * 64 + hl * 2]);
            ax += v.x; ay += v.y;
        }
        if (live) {
            float di = dinv[n];
            float ox = fmaxf(fmaf(di, ax, bx), 0.0f);
            float oy = fmaxf(fmaf(di, ay, by), 0.0f);
            *(float2*)&out[(size_t)n * 64 + hl * 2] = make_float2(ox, oy);
        }
    }
}

extern "C" void kernel_launch(void* const* d_in, const int* in_sizes, int n_in,
                              void* d_out, int out_size, void* d_ws, size_t ws_size,
                              hipStream_t stream) {
    const float* x  = (const float*)d_in[0];
    const int*   ei = (const int*)d_in[1];
    const float* W1 = (const float*)d_in[2];
    const float* b1 = (const float*)d_in[3];
    const float* W2 = (const float*)d_in[4];
    const float* b2 = (const float*)d_in[5];
    float* out = (float*)d_out;

    const int HID  = in_sizes[3];          // 128
    const int F_IN = in_sizes[2] / HID;    // 128
    const int N    = in_sizes[0] / F_IN;   // 50000
    const int E    = in_sizes[1] / 2;      // 1.6M
    (void)n_in; (void)out_size; (void)ws_size;

    const int* src = ei;
    const int* dst = ei + E;

    const int nbins = (N + 63) >> 6;       // 782

    // ---- carve workspace ----
    char* p = (char*)d_ws;
    auto carve = [&](size_t bytes) { void* q = (void*)p; p += (bytes + 255) & ~(size_t)255; return q; };
    int*            binCnt  = (int*)           carve((size_t)nbins * 4);
    float*          dinv    = (float*)         carve((size_t)N * 4);
    unsigned*       recs    = (unsigned*)      carve((size_t)nbins * BIN_CAP * 4);
    unsigned short* sortedG = (unsigned short*)carve((size_t)nbins * BIN_CAP * 2);
    int*            startG  = (int*)           carve((size_t)nbins * 65 * 4);
    __half*         bufG    = (__half*)        carve((size_t)N * 128 * 2);
    float*          bufB    = (float*)         carve((size_t)N * 128 * 4);

    hipMemsetAsync(binCnt, 0, (size_t)nbins * 4, stream);

    // ---- bin + single sort pass (no CSR, no global scatter) ----
    int numTiles = (E + TILE - 1) / TILE;
    size_t binLds = (size_t)nbins * 2 * 4;
    bin_kernel<<<numTiles, 256, binLds, stream>>>(src, dst, E, nbins, binCnt, recs);
    sort_bins<<<nbins, 256, 0, stream>>>(recs, binCnt, sortedG, startG, dinv, N);

    dim3 aggGrid(nbins, 2);

    // ---- layer 1: bufG = half(dinv*(x@W1)) ; bufB = relu(dinv*agg + b1) ----
    gemm_kernel<128><<<(N + 31) / 32, 256, 0, stream>>>(x, W1, dinv, bufG, N);
    agg_128<<<aggGrid, 512, 0, stream>>>(bufG, sortedG, startG, dinv, b1, bufB, N);

    // ---- layer 2: bufG = half(dinv*(bufB@W2)) ; out = relu(dinv*agg + b2) ----
    gemm_kernel<64><<<(N + 63) / 64, 256, 0, stream>>>(bufB, W2, dinv, bufG, N);
    agg_64<<<aggGrid, 512, 0, stream>>>(bufG, sortedG, startG, dinv, b2, out, N);
}

// Round 13
// 234.953 us; speedup vs baseline: 1.1780x; 1.1780x over previous
//
#include <hip/hip_runtime.h>
#include <hip/hip_fp16.h>

// ---------------------------------------------------------------------------
// GCN 2-layer forward: out = relu(A_hat @ relu(A_hat @ (X W1) + b1) W2 + b2)
// A_hat = D^-1/2 (A + I) D^-1/2.
// Normalization folded: g = dinv[row]*(X@W); agg_n = dinv[n]*(g[n]+sum g[src]).
// Pipeline: bin by dst>>6 -> sort_bins (per-bin LDS counting sort, once) ->
// MFMA fp16 GEMM (v_mfma_f32_16x16x32_f16, fp32 accum, dinv*fp16 epilogue) ->
// agg kernels bulk-load sorted u16 src lists and register-accumulate gathers.
// h1 kept fp16 end-to-end (R12: fp32 h1 round-trip = 51MB of traffic).
// Requires N <= 65536 (src packs into 16 bits).
// ---------------------------------------------------------------------------

#define TILE 8192      // edges per bin_kernel block
#define BIN_CAP 2560   // per-bin record capacity (mean 2046, sd ~45 -> 11 sigma)

typedef _Float16 half8 __attribute__((ext_vector_type(8)));
typedef float floatx4 __attribute__((ext_vector_type(4)));

// ---- bin edges by dst>>6: rec = (d&63)<<16 | s ----
__global__ __launch_bounds__(256) void bin_kernel(const int* __restrict__ src,
                                                  const int* __restrict__ dst, int E,
                                                  int nbins,
                                                  int* __restrict__ binCnt,
                                                  unsigned* __restrict__ recs) {
    extern __shared__ int lds[];           // cnt[nbins] | gbase[nbins]
    int* cnt = lds;
    int* gbase = lds + nbins;
    int tid = threadIdx.x;
    for (int i = tid; i < nbins; i += 256) cnt[i] = 0;
    __syncthreads();

    int t0 = blockIdx.x * TILE;
    int tEnd = min(t0 + TILE, E);

    for (int e = t0 + tid; e < tEnd; e += 256)
        atomicAdd(&cnt[dst[e] >> 6], 1);
    __syncthreads();

    for (int i = tid; i < nbins; i += 256) {
        int c = cnt[i];
        gbase[i] = (c > 0) ? atomicAdd(&binCnt[i], c) : 0;
        cnt[i] = 0;                        // reuse as local cursor
    }
    __syncthreads();

    for (int e = t0 + tid; e < tEnd; e += 256) {
        int d = dst[e];
        int s = src[e];
        int b = d >> 6;
        int r = atomicAdd(&cnt[b], 1);
        int g = gbase[b] + r;
        if (g < BIN_CAP)
            recs[(size_t)b * BIN_CAP + g] = ((unsigned)(d & 63) << 16) | (unsigned)s;
    }
}

// ---- per-bin counting sort (once): sorted u16 lists + starts + dinv ----
__global__ __launch_bounds__(256) void sort_bins(const unsigned* __restrict__ recs,
                                                 const int* __restrict__ binCnt,
                                                 unsigned short* __restrict__ sortedG,
                                                 int* __restrict__ startG,
                                                 float* __restrict__ dinv, int N) {
    __shared__ unsigned short sorted[BIN_CAP];
    __shared__ int c64[64];
    __shared__ int start[65];
    __shared__ int cursor[64];
    int b = blockIdx.x, tid = threadIdx.x;
    int lane = tid & 63, wave = tid >> 6;

    if (tid < 64) c64[tid] = 0;
    __syncthreads();
    int cnt = min(binCnt[b], BIN_CAP);
    const unsigned* bin = recs + (size_t)b * BIN_CAP;

    for (int i = tid; i < cnt; i += 256)
        atomicAdd(&c64[bin[i] >> 16], 1);
    __syncthreads();

    if (wave == 0) {
        int c = c64[lane];
        int v = c;
        #pragma unroll
        for (int off = 1; off < 64; off <<= 1) {
            int t = __shfl_up(v, off);
            if (lane >= off) v += t;
        }
        start[lane] = v - c;
        cursor[lane] = v - c;
        startG[b * 65 + lane] = v - c;
        if (lane == 63) { start[64] = v; startG[b * 65 + 64] = v; }
        int n = (b << 6) + lane;
        if (n < N) dinv[n] = rsqrtf((float)(c + 1));   // +1 = self loop
    }
    __syncthreads();

    for (int i = tid; i < cnt; i += 256) {
        unsigned r = bin[i];
        int pos = atomicAdd(&cursor[r >> 16], 1);
        sorted[pos] = (unsigned short)(r & 0xFFFFu);
    }
    __syncthreads();
    unsigned short* sg = sortedG + (size_t)b * BIN_CAP;
    for (int i = tid; i < cnt; i += 256) sg[i] = sorted[i];
}

// ---- MFMA fp16 GEMM: Y[r,:] = half( dinv[r] * (X[r,:] @ W) ) ----
// 64 rows x COLS per block, 256 thr (4 waves, wave owns 16 rows).
// A staged fp16 in LDS [64][LDA]; W^T staged fp16 [COLS][LDA].
// Frag layouts (guide §3): A[m=lane&15][k=quad*8+j]; B[n=lane&15][k=quad*8+j];
// C/D col=lane&15, row=quad*4+reg.
template <int COLS, bool FP32IN>
__global__ __launch_bounds__(256) void gemm_mfma(const void* __restrict__ Xv,
                                                 const float* __restrict__ W,
                                                 const float* __restrict__ dinv,
                                                 __half* __restrict__ Y, int N) {
    constexpr int LDA = 136;               // halfs; 272B row stride, 16B aligned
    __shared__ __align__(16) _Float16 aT[64 * LDA];
    __shared__ __align__(16) _Float16 bT[COLS * LDA];

    int tid = threadIdx.x;
    int lane = tid & 63, wave = tid >> 6;
    int row0 = blockIdx.x * 64;

    // stage A (64 rows x 128 k) as fp16
    for (int i = tid * 4; i < 64 * 128; i += 1024) {
        int r = i >> 7, k = i & 127;
        int gr = row0 + r;
        if (FP32IN) {
            float4 v = make_float4(0.f, 0.f, 0.f, 0.f);
            if (gr < N) v = *(const float4*)&((const float*)Xv)[(size_t)gr * 128 + k];
            __half2 p0 = __floats2half2_rn(v.x, v.y);
            __half2 p1 = __floats2half2_rn(v.z, v.w);
            *(uint2*)&aT[r * LDA + k] = make_uint2(*(uint*)&p0, *(uint*)&p1);
        } else {
            ushort4 u = make_ushort4(0, 0, 0, 0);
            if (gr < N) u = *(const ushort4*)&((const __half*)Xv)[(size_t)gr * 128 + k];
            *(ushort4*)&aT[r * LDA + k] = u;
        }
    }
    // stage W^T (bT[n][k]) as fp16
    for (int i = tid; i < 128 * COLS; i += 256) {
        int k = i / COLS, n = i % COLS;
        bT[n * LDA + k] = (_Float16)W[i];
    }
    __syncthreads();

    constexpr int NT = COLS / 16;          // col tiles per wave
    floatx4 acc[NT];
    #pragma unroll
    for (int t = 0; t < NT; t++) acc[t] = (floatx4){0.f, 0.f, 0.f, 0.f};

    int m = lane & 15, q = lane >> 4;
    const _Float16* arow = &aT[(wave * 16 + m) * LDA + q * 8];

    #pragma unroll
    for (int ks = 0; ks < 4; ks++) {       // K = ks*32 + q*8 + j
        half8 af = *(const half8*)&arow[ks * 32];
        #pragma unroll
        for (int t = 0; t < NT; t++) {
            half8 bf = *(const half8*)&bT[(t * 16 + m) * LDA + ks * 32 + q * 8];
            acc[t] = __builtin_amdgcn_mfma_f32_16x16x32_f16(af, bf, acc[t], 0, 0, 0);
        }
    }
    __syncthreads();                       // done reading aT; reuse as out tile

    // epilogue: dinv-scale, fp16, into LDS [64][LDA], then coalesced store
    float dv[4];
    #pragma unroll
    for (int r = 0; r < 4; r++) {
        int gr = row0 + wave * 16 + q * 4 + r;
        dv[r] = (gr < N) ? dinv[gr] : 0.0f;
    }
    #pragma unroll
    for (int t = 0; t < NT; t++)
        #pragma unroll
        for (int r = 0; r < 4; r++)
            aT[(wave * 16 + q * 4 + r) * LDA + t * 16 + m] = (_Float16)(dv[r] * acc[t][r]);
    __syncthreads();

    for (int i = tid; i < 64 * (COLS / 2); i += 256) {
        int r = i / (COLS / 2), c = i % (COLS / 2);   // c indexes half2
        int gr = row0 + r;
        if (gr < N)
            ((uint*)Y)[(size_t)gr * (COLS / 2) + c] = *(uint*)&aT[r * LDA + c * 2];
    }
}

// ---- agg F=128: block (b, half) = 32 rows; wave owns 4 rows; fp16 h1 out ----
__global__ __launch_bounds__(512) void agg_128(const __half* __restrict__ G,
                                               const unsigned short* __restrict__ sortedG,
                                               const int* __restrict__ startG,
                                               const float* __restrict__ dinv,
                                               const float* __restrict__ bias,
                                               __half* __restrict__ out, int N) {
    __shared__ unsigned short buf[BIN_CAP];
    __shared__ int st[33];
    int b = blockIdx.x, half_ = blockIdx.y;
    int tid = threadIdx.x, lane = tid & 63, wave = tid >> 6;
    int r0 = half_ * 32;

    if (tid < 33) st[tid] = startG[b * 65 + r0 + tid];
    __syncthreads();
    int S0 = st[0], S1 = st[32];
    const unsigned short* sg = sortedG + (size_t)b * BIN_CAP;
    for (int i = tid; i < S1 - S0; i += 512) buf[i] = sg[S0 + i];
    __syncthreads();

    float bx = bias[lane * 2], by = bias[lane * 2 + 1];
    for (int rr = 0; rr < 4; rr++) {
        int row = wave * 4 + rr;
        int n = (b << 6) + r0 + row;
        if (n >= N) continue;
        int jst = st[row] - S0, jen = st[row + 1] - S0;
        float2 self = __half22float2(*(const __half2*)&G[(size_t)n * 128 + lane * 2]);
        float ax = self.x, ay = self.y;
        int j = jst;
        for (; j + 8 <= jen; j += 8) {
            int s0 = buf[j],     s1 = buf[j + 1];
            int s2 = buf[j + 2], s3 = buf[j + 3];
            int s4 = buf[j + 4], s5 = buf[j + 5];
            int s6 = buf[j + 6], s7 = buf[j + 7];
            float2 v0 = __half22float2(*(const __half2*)&G[(size_t)s0 * 128 + lane * 2]);
            float2 v1 = __half22float2(*(const __half2*)&G[(size_t)s1 * 128 + lane * 2]);
            float2 v2 = __half22float2(*(const __half2*)&G[(size_t)s2 * 128 + lane * 2]);
            float2 v3 = __half22float2(*(const __half2*)&G[(size_t)s3 * 128 + lane * 2]);
            float2 v4 = __half22float2(*(const __half2*)&G[(size_t)s4 * 128 + lane * 2]);
            float2 v5 = __half22float2(*(const __half2*)&G[(size_t)s5 * 128 + lane * 2]);
            float2 v6 = __half22float2(*(const __half2*)&G[(size_t)s6 * 128 + lane * 2]);
            float2 v7 = __half22float2(*(const __half2*)&G[(size_t)s7 * 128 + lane * 2]);
            ax += ((v0.x + v1.x) + (v2.x + v3.x)) + ((v4.x + v5.x) + (v6.x + v7.x));
            ay += ((v0.y + v1.y) + (v2.y + v3.y)) + ((v4.y + v5.y) + (v6.y + v7.y));
        }
        for (; j < jen; j++) {
            int s = buf[j];
            float2 v = __half22float2(*(const __half2*)&G[(size_t)s * 128 + lane * 2]);
            ax += v.x; ay += v.y;
        }
        float di = dinv[n];
        float ox = fmaxf(fmaf(di, ax, bx), 0.0f);
        float oy = fmaxf(fmaf(di, ay, by), 0.0f);
        *(__half2*)&out[(size_t)n * 128 + lane * 2] = __floats2half2_rn(ox, oy);
    }
}

// ---- agg F=64: block (b, half) = 32 rows; HALF-wave (32 lanes, half2)/node ----
__global__ __launch_bounds__(512) void agg_64(const __half* __restrict__ G,
                                              const unsigned short* __restrict__ sortedG,
                                              const int* __restrict__ startG,
                                              const float* __restrict__ dinv,
                                              const float* __restrict__ bias,
                                              float* __restrict__ out, int N) {
    __shared__ unsigned short buf[BIN_CAP];
    __shared__ int st[33];
    int b = blockIdx.x, half_ = blockIdx.y;
    int tid = threadIdx.x, lane = tid & 63, wave = tid >> 6;
    int hl = lane & 31, side = lane >> 5;
    int r0 = half_ * 32;

    if (tid < 33) st[tid] = startG[b * 65 + r0 + tid];
    __syncthreads();
    int S0 = st[0], S1 = st[32];
    const unsigned short* sg = sortedG + (size_t)b * BIN_CAP;
    for (int i = tid; i < S1 - S0; i += 512) buf[i] = sg[S0 + i];
    __syncthreads();

    float bx = bias[hl * 2], by = bias[hl * 2 + 1];
    for (int pp = 0; pp < 2; pp++) {
        int row = wave * 4 + pp * 2 + side;
        int n = (b << 6) + r0 + row;
        bool live = (n < N);
        int jst = live ? (st[row] - S0) : 0;
        int jen = live ? (st[row + 1] - S0) : 0;
        float ax = 0.0f, ay = 0.0f;
        if (live) {
            float2 self = __half22float2(*(const __half2*)&G[(size_t)n * 64 + hl * 2]);
            ax = self.x; ay = self.y;
        }
        int j = jst;
        for (; j + 4 <= jen; j += 4) {
            int s0 = buf[j],     s1 = buf[j + 1];
            int s2 = buf[j + 2], s3 = buf[j + 3];
            float2 v0 = __half22float2(*(const __half2*)&G[(size_t)s0 * 64 + hl * 2]);
            float2 v1 = __half22float2(*(const __half2*)&G[(size_t)s1 * 64 + hl * 2]);
            float2 v2 = __half22float2(*(const __half2*)&G[(size_t)s2 * 64 + hl * 2]);
            float2 v3 = __half22float2(*(const __half2*)&G[(size_t)s3 * 64 + hl * 2]);
            ax += (v0.x + v1.x) + (v2.x + v3.x);
            ay += (v0.y + v1.y) + (v2.y + v3.y);
        }
        for (; j < jen; j++) {
            int s = buf[j];
            float2 v = __half22float2(*(const __half2*)&G[(size_t)s * 64 + hl * 2]);
            ax += v.x; ay += v.y;
        }
        if (live) {
            float di = dinv[n];
            float ox = fmaxf(fmaf(di, ax, bx), 0.0f);
            float oy = fmaxf(fmaf(di, ay, by), 0.0f);
            *(float2*)&out[(size_t)n * 64 + hl * 2] = make_float2(ox, oy);
        }
    }
}

extern "C" void kernel_launch(void* const* d_in, const int* in_sizes, int n_in,
                              void* d_out, int out_size, void* d_ws, size_t ws_size,
                              hipStream_t stream) {
    const float* x  = (const float*)d_in[0];
    const int*   ei = (const int*)d_in[1];
    const float* W1 = (const float*)d_in[2];
    const float* b1 = (const float*)d_in[3];
    const float* W2 = (const float*)d_in[4];
    const float* b2 = (const float*)d_in[5];
    float* out = (float*)d_out;

    const int HID  = in_sizes[3];          // 128
    const int F_IN = in_sizes[2] / HID;    // 128
    const int N    = in_sizes[0] / F_IN;   // 50000
    const int E    = in_sizes[1] / 2;      // 1.6M
    (void)n_in; (void)out_size; (void)ws_size; (void)F_IN;

    const int* src = ei;
    const int* dst = ei + E;

    const int nbins = (N + 63) >> 6;       // 782

    // ---- carve workspace ----
    char* p = (char*)d_ws;
    auto carve = [&](size_t bytes) { void* q = (void*)p; p += (bytes + 255) & ~(size_t)255; return q; };
    int*            binCnt  = (int*)           carve((size_t)nbins * 4);
    float*          dinv    = (float*)         carve((size_t)N * 4);
    unsigned*       recs    = (unsigned*)      carve((size_t)nbins * BIN_CAP * 4);
    unsigned short* sortedG = (unsigned short*)carve((size_t)nbins * BIN_CAP * 2);
    int*            startG  = (int*)           carve((size_t)nbins * 65 * 4);
    __half*         bufG    = (__half*)        carve((size_t)N * 128 * 2);  // g (gather table)
    __half*         bufB    = (__half*)        carve((size_t)N * 128 * 2);  // h1 fp16

    hipMemsetAsync(binCnt, 0, (size_t)nbins * 4, stream);

    // ---- bin + single sort pass ----
    int numTiles = (E + TILE - 1) / TILE;
    size_t binLds = (size_t)nbins * 2 * 4;
    bin_kernel<<<numTiles, 256, binLds, stream>>>(src, dst, E, nbins, binCnt, recs);
    sort_bins<<<nbins, 256, 0, stream>>>(recs, binCnt, sortedG, startG, dinv, N);

    dim3 aggGrid(nbins, 2);
    int gemmGrid = (N + 63) / 64;

    // ---- layer 1: bufG = half(dinv*(x@W1)) ; bufB = h1 = relu(dinv*agg + b1) ----
    gemm_mfma<128, true><<<gemmGrid, 256, 0, stream>>>(x, W1, dinv, bufG, N);
    agg_128<<<aggGrid, 512, 0, stream>>>(bufG, sortedG, startG, dinv, b1, bufB, N);

    // ---- layer 2: bufG = half(dinv*(h1@W2)) ; out = relu(dinv*agg + b2) ----
    gemm_mfma<64, false><<<gemmGrid, 256, 0, stream>>>(bufB, W2, dinv, bufG, N);
    agg_64<<<aggGrid, 512, 0, stream>>>(bufG, sortedG, startG, dinv, b2, out, N);
}

// Round 14
// 218.237 us; speedup vs baseline: 1.2682x; 1.0766x over previous
//
#include <hip/hip_runtime.h>
#include <hip/hip_fp16.h>

// ---------------------------------------------------------------------------
// GCN 2-layer forward: out = relu(A_hat @ relu(A_hat @ (X W1) + b1) W2 + b2)
// A_hat = D^-1/2 (A + I) D^-1/2.
// Normalization folded: g = dinv[row]*(X@W); agg_n = dinv[n]*(g[n]+sum g[src]).
// Pipeline: bin by dst>>6 -> sort_bins (per-bin LDS counting sort, once) ->
// MFMA fp16 GEMM (v_mfma_f32_16x16x32_f16) -> agg kernels gather-accumulate.
// R14: agg gathers widened to 16B/lane (quad-of-lanes per edge, 4 edges in
// flight per wave instruction -> 1KB/load, the coalescing sweet spot), with
// shfl_xor cross-quad reduction. R13 showed agg latency/MLP-bound at 3 TB/s.
// Requires N <= 65536 (src packs into 16 bits).
// ---------------------------------------------------------------------------

#define TILE 8192      // edges per bin_kernel block
#define BIN_CAP 2560   // per-bin record capacity (mean 2046, sd ~45 -> 11 sigma)

typedef _Float16 half8 __attribute__((ext_vector_type(8)));
typedef float floatx4 __attribute__((ext_vector_type(4)));

// ---- bin edges by dst>>6: rec = (d&63)<<16 | s ----
__global__ __launch_bounds__(512) void bin_kernel(const int* __restrict__ src,
                                                  const int* __restrict__ dst, int E,
                                                  int nbins,
                                                  int* __restrict__ binCnt,
                                                  unsigned* __restrict__ recs) {
    extern __shared__ int lds[];           // cnt[nbins] | gbase[nbins]
    int* cnt = lds;
    int* gbase = lds + nbins;
    int tid = threadIdx.x;
    for (int i = tid; i < nbins; i += 512) cnt[i] = 0;
    __syncthreads();

    int t0 = blockIdx.x * TILE;
    int tEnd = min(t0 + TILE, E);

    for (int e = t0 + tid; e < tEnd; e += 512)
        atomicAdd(&cnt[dst[e] >> 6], 1);
    __syncthreads();

    for (int i = tid; i < nbins; i += 512) {
        int c = cnt[i];
        gbase[i] = (c > 0) ? atomicAdd(&binCnt[i], c) : 0;
        cnt[i] = 0;                        // reuse as local cursor
    }
    __syncthreads();

    for (int e = t0 + tid; e < tEnd; e += 512) {
        int d = dst[e];
        int s = src[e];
        int b = d >> 6;
        int r = atomicAdd(&cnt[b], 1);
        int g = gbase[b] + r;
        if (g < BIN_CAP)
            recs[(size_t)b * BIN_CAP + g] = ((unsigned)(d & 63) << 16) | (unsigned)s;
    }
}

// ---- per-bin counting sort (once): sorted u16 lists + starts + dinv ----
__global__ __launch_bounds__(512) void sort_bins(const unsigned* __restrict__ recs,
                                                 const int* __restrict__ binCnt,
                                                 unsigned short* __restrict__ sortedG,
                                                 int* __restrict__ startG,
                                                 float* __restrict__ dinv, int N) {
    __shared__ unsigned short sorted[BIN_CAP];
    __shared__ int c64[64];
    __shared__ int start[65];
    __shared__ int cursor[64];
    int b = blockIdx.x, tid = threadIdx.x;
    int lane = tid & 63, wave = tid >> 6;

    if (tid < 64) c64[tid] = 0;
    __syncthreads();
    int cnt = min(binCnt[b], BIN_CAP);
    const unsigned* bin = recs + (size_t)b * BIN_CAP;

    for (int i = tid; i < cnt; i += 512)
        atomicAdd(&c64[bin[i] >> 16], 1);
    __syncthreads();

    if (wave == 0) {
        int c = c64[lane];
        int v = c;
        #pragma unroll
        for (int off = 1; off < 64; off <<= 1) {
            int t = __shfl_up(v, off);
            if (lane >= off) v += t;
        }
        start[lane] = v - c;
        cursor[lane] = v - c;
        startG[b * 65 + lane] = v - c;
        if (lane == 63) { start[64] = v; startG[b * 65 + 64] = v; }
        int n = (b << 6) + lane;
        if (n < N) dinv[n] = rsqrtf((float)(c + 1));   // +1 = self loop
    }
    __syncthreads();

    for (int i = tid; i < cnt; i += 512) {
        unsigned r = bin[i];
        int pos = atomicAdd(&cursor[r >> 16], 1);
        sorted[pos] = (unsigned short)(r & 0xFFFFu);
    }
    __syncthreads();
    unsigned short* sg = sortedG + (size_t)b * BIN_CAP;
    for (int i = tid; i < cnt; i += 512) sg[i] = sorted[i];
}

// ---- MFMA fp16 GEMM: Y[r,:] = half( dinv[r] * (X[r,:] @ W) ) ----
template <int COLS, bool FP32IN>
__global__ __launch_bounds__(256) void gemm_mfma(const void* __restrict__ Xv,
                                                 const float* __restrict__ W,
                                                 const float* __restrict__ dinv,
                                                 __half* __restrict__ Y, int N) {
    constexpr int LDA = 136;               // halfs; 272B row stride, 16B aligned
    __shared__ __align__(16) _Float16 aT[64 * LDA];
    __shared__ __align__(16) _Float16 bT[COLS * LDA];

    int tid = threadIdx.x;
    int lane = tid & 63, wave = tid >> 6;
    int row0 = blockIdx.x * 64;

    for (int i = tid * 4; i < 64 * 128; i += 1024) {
        int r = i >> 7, k = i & 127;
        int gr = row0 + r;
        if (FP32IN) {
            float4 v = make_float4(0.f, 0.f, 0.f, 0.f);
            if (gr < N) v = *(const float4*)&((const float*)Xv)[(size_t)gr * 128 + k];
            __half2 p0 = __floats2half2_rn(v.x, v.y);
            __half2 p1 = __floats2half2_rn(v.z, v.w);
            *(uint2*)&aT[r * LDA + k] = make_uint2(*(uint*)&p0, *(uint*)&p1);
        } else {
            ushort4 u = make_ushort4(0, 0, 0, 0);
            if (gr < N) u = *(const ushort4*)&((const __half*)Xv)[(size_t)gr * 128 + k];
            *(ushort4*)&aT[r * LDA + k] = u;
        }
    }
    for (int i = tid; i < 128 * COLS; i += 256) {
        int k = i / COLS, n = i % COLS;
        bT[n * LDA + k] = (_Float16)W[i];
    }
    __syncthreads();

    constexpr int NT = COLS / 16;
    floatx4 acc[NT];
    #pragma unroll
    for (int t = 0; t < NT; t++) acc[t] = (floatx4){0.f, 0.f, 0.f, 0.f};

    int m = lane & 15, q = lane >> 4;
    const _Float16* arow = &aT[(wave * 16 + m) * LDA + q * 8];

    #pragma unroll
    for (int ks = 0; ks < 4; ks++) {
        half8 af = *(const half8*)&arow[ks * 32];
        #pragma unroll
        for (int t = 0; t < NT; t++) {
            half8 bf = *(const half8*)&bT[(t * 16 + m) * LDA + ks * 32 + q * 8];
            acc[t] = __builtin_amdgcn_mfma_f32_16x16x32_f16(af, bf, acc[t], 0, 0, 0);
        }
    }
    __syncthreads();

    float dv[4];
    #pragma unroll
    for (int r = 0; r < 4; r++) {
        int gr = row0 + wave * 16 + q * 4 + r;
        dv[r] = (gr < N) ? dinv[gr] : 0.0f;
    }
    #pragma unroll
    for (int t = 0; t < NT; t++)
        #pragma unroll
        for (int r = 0; r < 4; r++)
            aT[(wave * 16 + q * 4 + r) * LDA + t * 16 + m] = (_Float16)(dv[r] * acc[t][r]);
    __syncthreads();

    for (int i = tid; i < 64 * (COLS / 2); i += 256) {
        int r = i / (COLS / 2), c = i % (COLS / 2);
        int gr = row0 + r;
        if (gr < N)
            ((uint*)Y)[(size_t)gr * (COLS / 2) + c] = *(uint*)&aT[r * LDA + c * 2];
    }
}

// ---- agg F=128: block (b, half) = 32 rows; wave owns 4 rows ----
// quad-of-lanes per edge: ql=lane&15 owns 8 feats (16B), quad=lane>>4 strides
// edges by 4 -> 4 rows in flight per load instruction (1KB/wave).
__global__ __launch_bounds__(512) void agg_128(const __half* __restrict__ G,
                                               const unsigned short* __restrict__ sortedG,
                                               const int* __restrict__ startG,
                                               const float* __restrict__ dinv,
                                               const float* __restrict__ bias,
                                               __half* __restrict__ out, int N) {
    __shared__ unsigned short buf[BIN_CAP];
    __shared__ int st[33];
    int b = blockIdx.x, half_ = blockIdx.y;
    int tid = threadIdx.x, lane = tid & 63, wave = tid >> 6;
    int ql = lane & 15, quad = lane >> 4;
    int r0 = half_ * 32;

    if (tid < 33) st[tid] = startG[b * 65 + r0 + tid];
    __syncthreads();
    int S0 = st[0], S1 = st[32];
    const unsigned short* sg = sortedG + (size_t)b * BIN_CAP;
    for (int i = tid; i < S1 - S0; i += 512) buf[i] = sg[S0 + i];
    __syncthreads();

    // bias slice for this lane's 8 features
    float bb[8];
    #pragma unroll
    for (int k = 0; k < 4; k++) {
        float2 t = *(const float2*)&bias[ql * 8 + k * 2];
        bb[k * 2] = t.x; bb[k * 2 + 1] = t.y;
    }

    for (int rr = 0; rr < 4; rr++) {
        int row = wave * 4 + rr;
        int n = (b << 6) + r0 + row;
        if (n >= N) continue;
        int jst = st[row] - S0, jen = st[row + 1] - S0;

        float ax[8] = {};
        int j = jst + quad;
        for (; j + 4 < jen; j += 8) {
            int sA = buf[j], sB = buf[j + 4];
            uint4 uA = *(const uint4*)&G[(size_t)sA * 128 + ql * 8];
            uint4 uB = *(const uint4*)&G[(size_t)sB * 128 + ql * 8];
            float2 f;
            f = __half22float2(*(__half2*)&uA.x); ax[0] += f.x; ax[1] += f.y;
            f = __half22float2(*(__half2*)&uA.y); ax[2] += f.x; ax[3] += f.y;
            f = __half22float2(*(__half2*)&uA.z); ax[4] += f.x; ax[5] += f.y;
            f = __half22float2(*(__half2*)&uA.w); ax[6] += f.x; ax[7] += f.y;
            f = __half22float2(*(__half2*)&uB.x); ax[0] += f.x; ax[1] += f.y;
            f = __half22float2(*(__half2*)&uB.y); ax[2] += f.x; ax[3] += f.y;
            f = __half22float2(*(__half2*)&uB.z); ax[4] += f.x; ax[5] += f.y;
            f = __half22float2(*(__half2*)&uB.w); ax[6] += f.x; ax[7] += f.y;
        }
        for (; j < jen; j += 4) {
            int s = buf[j];
            uint4 u = *(const uint4*)&G[(size_t)s * 128 + ql * 8];
            float2 f;
            f = __half22float2(*(__half2*)&u.x); ax[0] += f.x; ax[1] += f.y;
            f = __half22float2(*(__half2*)&u.y); ax[2] += f.x; ax[3] += f.y;
            f = __half22float2(*(__half2*)&u.z); ax[4] += f.x; ax[5] += f.y;
            f = __half22float2(*(__half2*)&u.w); ax[6] += f.x; ax[7] += f.y;
        }
        // cross-quad reduction (all lanes end with full sums)
        #pragma unroll
        for (int k = 0; k < 8; k++) {
            ax[k] += __shfl_xor(ax[k], 16);
            ax[k] += __shfl_xor(ax[k], 32);
        }
        // self + bias + relu, quad 0 stores the row (16 lanes x 16B)
        if (quad == 0) {
            uint4 us = *(const uint4*)&G[(size_t)n * 128 + ql * 8];
            float2 f;
            f = __half22float2(*(__half2*)&us.x); ax[0] += f.x; ax[1] += f.y;
            f = __half22float2(*(__half2*)&us.y); ax[2] += f.x; ax[3] += f.y;
            f = __half22float2(*(__half2*)&us.z); ax[4] += f.x; ax[5] += f.y;
            f = __half22float2(*(__half2*)&us.w); ax[6] += f.x; ax[7] += f.y;
            float di = dinv[n];
            __half2 h[4];
            #pragma unroll
            for (int k = 0; k < 4; k++) {
                float o0 = fmaxf(fmaf(di, ax[k * 2],     bb[k * 2]),     0.0f);
                float o1 = fmaxf(fmaf(di, ax[k * 2 + 1], bb[k * 2 + 1]), 0.0f);
                h[k] = __floats2half2_rn(o0, o1);
            }
            *(uint4*)&out[(size_t)n * 128 + ql * 8] = *(uint4*)h;
        }
    }
}

// ---- agg F=64: block (b, half) = 32 rows; wave owns 4 rows ----
// octet-of-lanes per edge: ol=lane&7 owns 8 feats (16B), oct=lane>>3 strides
// edges by 8 -> 8 rows in flight per load instruction.
__global__ __launch_bounds__(512) void agg_64(const __half* __restrict__ G,
                                              const unsigned short* __restrict__ sortedG,
                                              const int* __restrict__ startG,
                                              const float* __restrict__ dinv,
                                              const float* __restrict__ bias,
                                              float* __restrict__ out, int N) {
    __shared__ unsigned short buf[BIN_CAP];
    __shared__ int st[33];
    int b = blockIdx.x, half_ = blockIdx.y;
    int tid = threadIdx.x, lane = tid & 63, wave = tid >> 6;
    int ol = lane & 7, oct = lane >> 3;
    int r0 = half_ * 32;

    if (tid < 33) st[tid] = startG[b * 65 + r0 + tid];
    __syncthreads();
    int S0 = st[0], S1 = st[32];
    const unsigned short* sg = sortedG + (size_t)b * BIN_CAP;
    for (int i = tid; i < S1 - S0; i += 512) buf[i] = sg[S0 + i];
    __syncthreads();

    float bb[8];
    #pragma unroll
    for (int k = 0; k < 4; k++) {
        float2 t = *(const float2*)&bias[ol * 8 + k * 2];
        bb[k * 2] = t.x; bb[k * 2 + 1] = t.y;
    }

    for (int rr = 0; rr < 4; rr++) {
        int row = wave * 4 + rr;
        int n = (b << 6) + r0 + row;
        if (n >= N) continue;
        int jst = st[row] - S0, jen = st[row + 1] - S0;

        float ax[8] = {};
        int j = jst + oct;
        for (; j + 8 < jen; j += 16) {
            int sA = buf[j], sB = buf[j + 8];
            uint4 uA = *(const uint4*)&G[(size_t)sA * 64 + ol * 8];
            uint4 uB = *(const uint4*)&G[(size_t)sB * 64 + ol * 8];
            float2 f;
            f = __half22float2(*(__half2*)&uA.x); ax[0] += f.x; ax[1] += f.y;
            f = __half22float2(*(__half2*)&uA.y); ax[2] += f.x; ax[3] += f.y;
            f = __half22float2(*(__half2*)&uA.z); ax[4] += f.x; ax[5] += f.y;
            f = __half22float2(*(__half2*)&uA.w); ax[6] += f.x; ax[7] += f.y;
            f = __half22float2(*(__half2*)&uB.x); ax[0] += f.x; ax[1] += f.y;
            f = __half22float2(*(__half2*)&uB.y); ax[2] += f.x; ax[3] += f.y;
            f = __half22float2(*(__half2*)&uB.z); ax[4] += f.x; ax[5] += f.y;
            f = __half22float2(*(__half2*)&uB.w); ax[6] += f.x; ax[7] += f.y;
        }
        for (; j < jen; j += 8) {
            int s = buf[j];
            uint4 u = *(const uint4*)&G[(size_t)s * 64 + ol * 8];
            float2 f;
            f = __half22float2(*(__half2*)&u.x); ax[0] += f.x; ax[1] += f.y;
            f = __half22float2(*(__half2*)&u.y); ax[2] += f.x; ax[3] += f.y;
            f = __half22float2(*(__half2*)&u.z); ax[4] += f.x; ax[5] += f.y;
            f = __half22float2(*(__half2*)&u.w); ax[6] += f.x; ax[7] += f.y;
        }
        #pragma unroll
        for (int k = 0; k < 8; k++) {
            ax[k] += __shfl_xor(ax[k], 8);
            ax[k] += __shfl_xor(ax[k], 16);
            ax[k] += __shfl_xor(ax[k], 32);
        }
        if (oct < 2) {
            // self + bias + relu; oct0 stores feats [ol*8..+3], oct1 [+4..+7]
            uint4 us = *(const uint4*)&G[(size_t)n * 64 + ol * 8];
            float2 f;
            f = __half22float2(*(__half2*)&us.x); ax[0] += f.x; ax[1] += f.y;
            f = __half22float2(*(__half2*)&us.y); ax[2] += f.x; ax[3] += f.y;
            f = __half22float2(*(__half2*)&us.z); ax[4] += f.x; ax[5] += f.y;
            f = __half22float2(*(__half2*)&us.w); ax[6] += f.x; ax[7] += f.y;
            float di = dinv[n];
            float o[8];
            #pragma unroll
            for (int k = 0; k < 8; k++)
                o[k] = fmaxf(fmaf(di, ax[k], bb[k]), 0.0f);
            if (oct == 0)
                *(float4*)&out[(size_t)n * 64 + ol * 8] = make_float4(o[0], o[1], o[2], o[3]);
            else
                *(float4*)&out[(size_t)n * 64 + ol * 8 + 4] = make_float4(o[4], o[5], o[6], o[7]);
        }
    }
}

extern "C" void kernel_launch(void* const* d_in, const int* in_sizes, int n_in,
                              void* d_out, int out_size, void* d_ws, size_t ws_size,
                              hipStream_t stream) {
    const float* x  = (const float*)d_in[0];
    const int*   ei = (const int*)d_in[1];
    const float* W1 = (const float*)d_in[2];
    const float* b1 = (const float*)d_in[3];
    const float* W2 = (const float*)d_in[4];
    const float* b2 = (const float*)d_in[5];
    float* out = (float*)d_out;

    const int HID  = in_sizes[3];          // 128
    const int F_IN = in_sizes[2] / HID;    // 128
    const int N    = in_sizes[0] / F_IN;   // 50000
    const int E    = in_sizes[1] / 2;      // 1.6M
    (void)n_in; (void)out_size; (void)ws_size; (void)F_IN;

    const int* src = ei;
    const int* dst = ei + E;

    const int nbins = (N + 63) >> 6;       // 782

    // ---- carve workspace ----
    char* p = (char*)d_ws;
    auto carve = [&](size_t bytes) { void* q = (void*)p; p += (bytes + 255) & ~(size_t)255; return q; };
    int*            binCnt  = (int*)           carve((size_t)nbins * 4);
    float*          dinv    = (float*)         carve((size_t)N * 4);
    unsigned*       recs    = (unsigned*)      carve((size_t)nbins * BIN_CAP * 4);
    unsigned short* sortedG = (unsigned short*)carve((size_t)nbins * BIN_CAP * 2);
    int*            startG  = (int*)           carve((size_t)nbins * 65 * 4);
    __half*         bufG    = (__half*)        carve((size_t)N * 128 * 2);  // gather table
    __half*         bufB    = (__half*)        carve((size_t)N * 128 * 2);  // h1 fp16

    hipMemsetAsync(binCnt, 0, (size_t)nbins * 4, stream);

    // ---- bin + single sort pass ----
    int numTiles = (E + TILE - 1) / TILE;
    size_t binLds = (size_t)nbins * 2 * 4;
    bin_kernel<<<numTiles, 512, binLds, stream>>>(src, dst, E, nbins, binCnt, recs);
    sort_bins<<<nbins, 512, 0, stream>>>(recs, binCnt, sortedG, startG, dinv, N);

    dim3 aggGrid(nbins, 2);
    int gemmGrid = (N + 63) / 64;

    // ---- layer 1 ----
    gemm_mfma<128, true><<<gemmGrid, 256, 0, stream>>>(x, W1, dinv, bufG, N);
    agg_128<<<aggGrid, 512, 0, stream>>>(bufG, sortedG, startG, dinv, b1, bufB, N);

    // ---- layer 2 ----
    gemm_mfma<64, false><<<gemmGrid, 256, 0, stream>>>(bufB, W2, dinv, bufG, N);
    agg_64<<<aggGrid, 512, 0, stream>>>(bufG, sortedG, startG, dinv, b2, out, N);
}

// Round 15
// 213.531 us; speedup vs baseline: 1.2961x; 1.0220x over previous
//
#include <hip/hip_runtime.h>
#include <hip/hip_fp16.h>

// ---------------------------------------------------------------------------
// GCN 2-layer forward: out = relu(A_hat @ relu(A_hat @ (X W1) + b1) W2 + b2)
// A_hat = D^-1/2 (A + I) D^-1/2.
// Normalization folded: g = dinv[row]*(X@W); agg_n = dinv[n]*(g[n]+sum g[src]).
// Pipeline: bin by dst>>6 -> sort_bins (per-bin LDS counting sort, once) ->
// gemm_mfma (layer-1) -> agg_gemm_fused (layer-1 agg + layer-2 GEMM in one
// block per bin; h1 lives only in LDS) -> agg_64.
// R15: fused h1: R14 showed aggs near the ~3.3TB/s L2-miss-path floor, so the
// win is removing the h1 HBM round-trip (25MB) + one dispatch.
// Requires N <= 65536 (src packs into 16 bits).
// ---------------------------------------------------------------------------

#define TILE 8192      // edges per bin_kernel block
#define BIN_CAP 2560   // per-bin record capacity (mean 2046, sd ~45 -> 11 sigma)

typedef _Float16 half8 __attribute__((ext_vector_type(8)));
typedef float floatx4 __attribute__((ext_vector_type(4)));

// ---- bin edges by dst>>6: rec = (d&63)<<16 | s ----
__global__ __launch_bounds__(512) void bin_kernel(const int* __restrict__ src,
                                                  const int* __restrict__ dst, int E,
                                                  int nbins,
                                                  int* __restrict__ binCnt,
                                                  unsigned* __restrict__ recs) {
    extern __shared__ int lds[];           // cnt[nbins] | gbase[nbins]
    int* cnt = lds;
    int* gbase = lds + nbins;
    int tid = threadIdx.x;
    for (int i = tid; i < nbins; i += 512) cnt[i] = 0;
    __syncthreads();

    int t0 = blockIdx.x * TILE;
    int tEnd = min(t0 + TILE, E);

    for (int e = t0 + tid; e < tEnd; e += 512)
        atomicAdd(&cnt[dst[e] >> 6], 1);
    __syncthreads();

    for (int i = tid; i < nbins; i += 512) {
        int c = cnt[i];
        gbase[i] = (c > 0) ? atomicAdd(&binCnt[i], c) : 0;
        cnt[i] = 0;                        // reuse as local cursor
    }
    __syncthreads();

    for (int e = t0 + tid; e < tEnd; e += 512) {
        int d = dst[e];
        int s = src[e];
        int b = d >> 6;
        int r = atomicAdd(&cnt[b], 1);
        int g = gbase[b] + r;
        if (g < BIN_CAP)
            recs[(size_t)b * BIN_CAP + g] = ((unsigned)(d & 63) << 16) | (unsigned)s;
    }
}

// ---- per-bin counting sort (once): sorted u16 lists + starts + dinv ----
__global__ __launch_bounds__(512) void sort_bins(const unsigned* __restrict__ recs,
                                                 const int* __restrict__ binCnt,
                                                 unsigned short* __restrict__ sortedG,
                                                 int* __restrict__ startG,
                                                 float* __restrict__ dinv, int N) {
    __shared__ unsigned short sorted[BIN_CAP];
    __shared__ int c64[64];
    __shared__ int start[65];
    __shared__ int cursor[64];
    int b = blockIdx.x, tid = threadIdx.x;
    int lane = tid & 63, wave = tid >> 6;

    if (tid < 64) c64[tid] = 0;
    __syncthreads();
    int cnt = min(binCnt[b], BIN_CAP);
    const unsigned* bin = recs + (size_t)b * BIN_CAP;

    for (int i = tid; i < cnt; i += 512)
        atomicAdd(&c64[bin[i] >> 16], 1);
    __syncthreads();

    if (wave == 0) {
        int c = c64[lane];
        int v = c;
        #pragma unroll
        for (int off = 1; off < 64; off <<= 1) {
            int t = __shfl_up(v, off);
            if (lane >= off) v += t;
        }
        start[lane] = v - c;
        cursor[lane] = v - c;
        startG[b * 65 + lane] = v - c;
        if (lane == 63) { start[64] = v; startG[b * 65 + 64] = v; }
        int n = (b << 6) + lane;
        if (n < N) dinv[n] = rsqrtf((float)(c + 1));   // +1 = self loop
    }
    __syncthreads();

    for (int i = tid; i < cnt; i += 512) {
        unsigned r = bin[i];
        int pos = atomicAdd(&cursor[r >> 16], 1);
        sorted[pos] = (unsigned short)(r & 0xFFFFu);
    }
    __syncthreads();
    unsigned short* sg = sortedG + (size_t)b * BIN_CAP;
    for (int i = tid; i < cnt; i += 512) sg[i] = sorted[i];
}

// ---- MFMA fp16 GEMM (layer 1): Y[r,:] = half( dinv[r] * (X[r,:] @ W) ) ----
template <int COLS, bool FP32IN>
__global__ __launch_bounds__(256) void gemm_mfma(const void* __restrict__ Xv,
                                                 const float* __restrict__ W,
                                                 const float* __restrict__ dinv,
                                                 __half* __restrict__ Y, int N) {
    constexpr int LDA = 136;               // halfs; 272B row stride, 16B aligned
    __shared__ __align__(16) _Float16 aT[64 * LDA];
    __shared__ __align__(16) _Float16 bT[COLS * LDA];

    int tid = threadIdx.x;
    int lane = tid & 63, wave = tid >> 6;
    int row0 = blockIdx.x * 64;

    for (int i = tid * 4; i < 64 * 128; i += 1024) {
        int r = i >> 7, k = i & 127;
        int gr = row0 + r;
        if (FP32IN) {
            float4 v = make_float4(0.f, 0.f, 0.f, 0.f);
            if (gr < N) v = *(const float4*)&((const float*)Xv)[(size_t)gr * 128 + k];
            __half2 p0 = __floats2half2_rn(v.x, v.y);
            __half2 p1 = __floats2half2_rn(v.z, v.w);
            *(uint2*)&aT[r * LDA + k] = make_uint2(*(uint*)&p0, *(uint*)&p1);
        } else {
            ushort4 u = make_ushort4(0, 0, 0, 0);
            if (gr < N) u = *(const ushort4*)&((const __half*)Xv)[(size_t)gr * 128 + k];
            *(ushort4*)&aT[r * LDA + k] = u;
        }
    }
    for (int i = tid; i < 128 * COLS; i += 256) {
        int k = i / COLS, n = i % COLS;
        bT[n * LDA + k] = (_Float16)W[i];
    }
    __syncthreads();

    constexpr int NT = COLS / 16;
    floatx4 acc[NT];
    #pragma unroll
    for (int t = 0; t < NT; t++) acc[t] = (floatx4){0.f, 0.f, 0.f, 0.f};

    int m = lane & 15, q = lane >> 4;
    const _Float16* arow = &aT[(wave * 16 + m) * LDA + q * 8];

    #pragma unroll
    for (int ks = 0; ks < 4; ks++) {
        half8 af = *(const half8*)&arow[ks * 32];
        #pragma unroll
        for (int t = 0; t < NT; t++) {
            half8 bf = *(const half8*)&bT[(t * 16 + m) * LDA + ks * 32 + q * 8];
            acc[t] = __builtin_amdgcn_mfma_f32_16x16x32_f16(af, bf, acc[t], 0, 0, 0);
        }
    }
    __syncthreads();

    float dv[4];
    #pragma unroll
    for (int r = 0; r < 4; r++) {
        int gr = row0 + wave * 16 + q * 4 + r;
        dv[r] = (gr < N) ? dinv[gr] : 0.0f;
    }
    #pragma unroll
    for (int t = 0; t < NT; t++)
        #pragma unroll
        for (int r = 0; r < 4; r++)
            aT[(wave * 16 + q * 4 + r) * LDA + t * 16 + m] = (_Float16)(dv[r] * acc[t][r]);
    __syncthreads();

    for (int i = tid; i < 64 * (COLS / 2); i += 256) {
        int r = i / (COLS / 2), c = i % (COLS / 2);
        int gr = row0 + r;
        if (gr < N)
            ((uint*)Y)[(size_t)gr * (COLS / 2) + c] = *(uint*)&aT[r * LDA + c * 2];
    }
}

// ---- FUSED: layer-1 aggregation (64-node bin) + layer-2 GEMM ----
// Phase 1: 8 waves x 8 rows, quad-of-lanes gathers (16B/lane), shfl_xor
// reduce, relu'd h1 row -> LDS tile hT[64][LDH] (fp16). h1 never hits HBM.
// Phase 2: hT @ W2 via v_mfma_f32_16x16x32_f16 (16 tiles, 2 per wave),
// dinv-scaled fp16 epilogue -> Y2 (coalesced).
__global__ __launch_bounds__(512) void agg_gemm_fused(
        const __half* __restrict__ G,
        const unsigned short* __restrict__ sortedG,
        const int* __restrict__ startG,
        const float* __restrict__ dinv,
        const float* __restrict__ bias,     // b1
        const float* __restrict__ W2,       // [128][64] fp32
        __half* __restrict__ Y2, int N) {
    constexpr int LDH = 136;
    __shared__ unsigned short buf[BIN_CAP];
    __shared__ int st[65];
    __shared__ __align__(16) _Float16 hT[64 * LDH];   // h1 tile (rows x k)
    __shared__ __align__(16) _Float16 bT[64 * LDH];   // W2^T (cols x k)

    int b = blockIdx.x;
    int tid = threadIdx.x, lane = tid & 63, wave = tid >> 6;
    int ql = lane & 15, quad = lane >> 4;

    if (tid < 65) st[tid] = startG[b * 65 + tid];
    __syncthreads();
    int cnt = st[64];
    const unsigned short* sg = sortedG + (size_t)b * BIN_CAP;
    for (int i = tid; i < cnt; i += 512) buf[i] = sg[i];
    // stage W2^T: bT[n][k] = W2[k][n]
    for (int i = tid; i < 128 * 64; i += 512) {
        int k = i >> 6, n = i & 63;
        bT[n * LDH + k] = (_Float16)W2[i];
    }
    __syncthreads();

    // bias slice for this lane's 8 features
    float bb[8];
    #pragma unroll
    for (int k = 0; k < 4; k++) {
        float2 t = *(const float2*)&bias[ql * 8 + k * 2];
        bb[k * 2] = t.x; bb[k * 2 + 1] = t.y;
    }

    // ---- phase 1: aggregate 8 rows per wave into hT ----
    for (int rr = 0; rr < 8; rr++) {
        int row = wave * 8 + rr;
        int n = (b << 6) + row;
        if (n >= N) {
            if (quad == 0) {
                uint4 z = make_uint4(0, 0, 0, 0);
                *(uint4*)&hT[row * LDH + ql * 8] = z;
            }
            continue;
        }
        int jst = st[row], jen = st[row + 1];

        float ax[8] = {};
        int j = jst + quad;
        for (; j + 4 < jen; j += 8) {
            int sA = buf[j], sB = buf[j + 4];
            uint4 uA = *(const uint4*)&G[(size_t)sA * 128 + ql * 8];
            uint4 uB = *(const uint4*)&G[(size_t)sB * 128 + ql * 8];
            float2 f;
            f = __half22float2(*(__half2*)&uA.x); ax[0] += f.x; ax[1] += f.y;
            f = __half22float2(*(__half2*)&uA.y); ax[2] += f.x; ax[3] += f.y;
            f = __half22float2(*(__half2*)&uA.z); ax[4] += f.x; ax[5] += f.y;
            f = __half22float2(*(__half2*)&uA.w); ax[6] += f.x; ax[7] += f.y;
            f = __half22float2(*(__half2*)&uB.x); ax[0] += f.x; ax[1] += f.y;
            f = __half22float2(*(__half2*)&uB.y); ax[2] += f.x; ax[3] += f.y;
            f = __half22float2(*(__half2*)&uB.z); ax[4] += f.x; ax[5] += f.y;
            f = __half22float2(*(__half2*)&uB.w); ax[6] += f.x; ax[7] += f.y;
        }
        for (; j < jen; j += 4) {
            int s = buf[j];
            uint4 u = *(const uint4*)&G[(size_t)s * 128 + ql * 8];
            float2 f;
            f = __half22float2(*(__half2*)&u.x); ax[0] += f.x; ax[1] += f.y;
            f = __half22float2(*(__half2*)&u.y); ax[2] += f.x; ax[3] += f.y;
            f = __half22float2(*(__half2*)&u.z); ax[4] += f.x; ax[5] += f.y;
            f = __half22float2(*(__half2*)&u.w); ax[6] += f.x; ax[7] += f.y;
        }
        #pragma unroll
        for (int k = 0; k < 8; k++) {
            ax[k] += __shfl_xor(ax[k], 16);
            ax[k] += __shfl_xor(ax[k], 32);
        }
        if (quad == 0) {
            uint4 us = *(const uint4*)&G[(size_t)n * 128 + ql * 8];
            float2 f;
            f = __half22float2(*(__half2*)&us.x); ax[0] += f.x; ax[1] += f.y;
            f = __half22float2(*(__half2*)&us.y); ax[2] += f.x; ax[3] += f.y;
            f = __half22float2(*(__half2*)&us.z); ax[4] += f.x; ax[5] += f.y;
            f = __half22float2(*(__half2*)&us.w); ax[6] += f.x; ax[7] += f.y;
            float di = dinv[n];
            __half2 h[4];
            #pragma unroll
            for (int k = 0; k < 4; k++) {
                float o0 = fmaxf(fmaf(di, ax[k * 2],     bb[k * 2]),     0.0f);
                float o1 = fmaxf(fmaf(di, ax[k * 2 + 1], bb[k * 2 + 1]), 0.0f);
                h[k] = __floats2half2_rn(o0, o1);
            }
            *(uint4*)&hT[row * LDH + ql * 8] = *(uint4*)h;
        }
    }
    __syncthreads();

    // ---- phase 2: g2 = dinv * (hT @ W2), 64x64 out, 2 tiles per wave ----
    int m = lane & 15, q = lane >> 4;
    int mt = wave & 3, nt0 = (wave >> 2) * 2;
    floatx4 acc[2] = {(floatx4){0.f, 0.f, 0.f, 0.f}, (floatx4){0.f, 0.f, 0.f, 0.f}};
    const _Float16* arow = &hT[(mt * 16 + m) * LDH + q * 8];
    #pragma unroll
    for (int ks = 0; ks < 4; ks++) {
        half8 af = *(const half8*)&arow[ks * 32];
        #pragma unroll
        for (int t = 0; t < 2; t++) {
            half8 bf = *(const half8*)&bT[((nt0 + t) * 16 + m) * LDH + ks * 32 + q * 8];
            acc[t] = __builtin_amdgcn_mfma_f32_16x16x32_f16(af, bf, acc[t], 0, 0, 0);
        }
    }
    __syncthreads();                       // all MFMA reads of hT done

    float dv[4];
    #pragma unroll
    for (int r = 0; r < 4; r++) {
        int gr = (b << 6) + mt * 16 + q * 4 + r;
        dv[r] = (gr < N) ? dinv[gr] : 0.0f;
    }
    #pragma unroll
    for (int t = 0; t < 2; t++)
        #pragma unroll
        for (int r = 0; r < 4; r++)
            hT[(mt * 16 + q * 4 + r) * LDH + (nt0 + t) * 16 + m] = (_Float16)(dv[r] * acc[t][r]);
    __syncthreads();

    for (int i = tid; i < 64 * 32; i += 512) {
        int r = i >> 5, c = i & 31;        // c indexes half2
        int gr = (b << 6) + r;
        if (gr < N)
            ((uint*)Y2)[(size_t)gr * 32 + c] = *(uint*)&hT[r * LDH + c * 2];
    }
}

// ---- agg F=64 (layer 2): block (b, half) = 32 rows; octet scheme ----
__global__ __launch_bounds__(512) void agg_64(const __half* __restrict__ G,
                                              const unsigned short* __restrict__ sortedG,
                                              const int* __restrict__ startG,
                                              const float* __restrict__ dinv,
                                              const float* __restrict__ bias,
                                              float* __restrict__ out, int N) {
    __shared__ unsigned short buf[BIN_CAP];
    __shared__ int st[33];
    int b = blockIdx.x, half_ = blockIdx.y;
    int tid = threadIdx.x, lane = tid & 63, wave = tid >> 6;
    int ol = lane & 7, oct = lane >> 3;
    int r0 = half_ * 32;

    if (tid < 33) st[tid] = startG[b * 65 + r0 + tid];
    __syncthreads();
    int S0 = st[0], S1 = st[32];
    const unsigned short* sg = sortedG + (size_t)b * BIN_CAP;
    for (int i = tid; i < S1 - S0; i += 512) buf[i] = sg[S0 + i];
    __syncthreads();

    float bb[8];
    #pragma unroll
    for (int k = 0; k < 4; k++) {
        float2 t = *(const float2*)&bias[ol * 8 + k * 2];
        bb[k * 2] = t.x; bb[k * 2 + 1] = t.y;
    }

    for (int rr = 0; rr < 4; rr++) {
        int row = wave * 4 + rr;
        int n = (b << 6) + r0 + row;
        if (n >= N) continue;
        int jst = st[row] - S0, jen = st[row + 1] - S0;

        float ax[8] = {};
        int j = jst + oct;
        for (; j + 8 < jen; j += 16) {
            int sA = buf[j], sB = buf[j + 8];
            uint4 uA = *(const uint4*)&G[(size_t)sA * 64 + ol * 8];
            uint4 uB = *(const uint4*)&G[(size_t)sB * 64 + ol * 8];
            float2 f;
            f = __half22float2(*(__half2*)&uA.x); ax[0] += f.x; ax[1] += f.y;
            f = __half22float2(*(__half2*)&uA.y); ax[2] += f.x; ax[3] += f.y;
            f = __half22float2(*(__half2*)&uA.z); ax[4] += f.x; ax[5] += f.y;
            f = __half22float2(*(__half2*)&uA.w); ax[6] += f.x; ax[7] += f.y;
            f = __half22float2(*(__half2*)&uB.x); ax[0] += f.x; ax[1] += f.y;
            f = __half22float2(*(__half2*)&uB.y); ax[2] += f.x; ax[3] += f.y;
            f = __half22float2(*(__half2*)&uB.z); ax[4] += f.x; ax[5] += f.y;
            f = __half22float2(*(__half2*)&uB.w); ax[6] += f.x; ax[7] += f.y;
        }
        for (; j < jen; j += 8) {
            int s = buf[j];
            uint4 u = *(const uint4*)&G[(size_t)s * 64 + ol * 8];
            float2 f;
            f = __half22float2(*(__half2*)&u.x); ax[0] += f.x; ax[1] += f.y;
            f = __half22float2(*(__half2*)&u.y); ax[2] += f.x; ax[3] += f.y;
            f = __half22float2(*(__half2*)&u.z); ax[4] += f.x; ax[5] += f.y;
            f = __half22float2(*(__half2*)&u.w); ax[6] += f.x; ax[7] += f.y;
        }
        #pragma unroll
        for (int k = 0; k < 8; k++) {
            ax[k] += __shfl_xor(ax[k], 8);
            ax[k] += __shfl_xor(ax[k], 16);
            ax[k] += __shfl_xor(ax[k], 32);
        }
        if (oct < 2) {
            uint4 us = *(const uint4*)&G[(size_t)n * 64 + ol * 8];
            float2 f;
            f = __half22float2(*(__half2*)&us.x); ax[0] += f.x; ax[1] += f.y;
            f = __half22float2(*(__half2*)&us.y); ax[2] += f.x; ax[3] += f.y;
            f = __half22float2(*(__half2*)&us.z); ax[4] += f.x; ax[5] += f.y;
            f = __half22float2(*(__half2*)&us.w); ax[6] += f.x; ax[7] += f.y;
            float di = dinv[n];
            float o[8];
            #pragma unroll
            for (int k = 0; k < 8; k++)
                o[k] = fmaxf(fmaf(di, ax[k], bb[k]), 0.0f);
            if (oct == 0)
                *(float4*)&out[(size_t)n * 64 + ol * 8] = make_float4(o[0], o[1], o[2], o[3]);
            else
                *(float4*)&out[(size_t)n * 64 + ol * 8 + 4] = make_float4(o[4], o[5], o[6], o[7]);
        }
    }
}

extern "C" void kernel_launch(void* const* d_in, const int* in_sizes, int n_in,
                              void* d_out, int out_size, void* d_ws, size_t ws_size,
                              hipStream_t stream) {
    const float* x  = (const float*)d_in[0];
    const int*   ei = (const int*)d_in[1];
    const float* W1 = (const float*)d_in[2];
    const float* b1 = (const float*)d_in[3];
    const float* W2 = (const float*)d_in[4];
    const float* b2 = (const float*)d_in[5];
    float* out = (float*)d_out;

    const int HID  = in_sizes[3];          // 128
    const int F_IN = in_sizes[2] / HID;    // 128
    const int N    = in_sizes[0] / F_IN;   // 50000
    const int E    = in_sizes[1] / 2;      // 1.6M
    (void)n_in; (void)out_size; (void)ws_size; (void)F_IN;

    const int* src = ei;
    const int* dst = ei + E;

    const int nbins = (N + 63) >> 6;       // 782

    // ---- carve workspace ----
    char* p = (char*)d_ws;
    auto carve = [&](size_t bytes) { void* q = (void*)p; p += (bytes + 255) & ~(size_t)255; return q; };
    int*            binCnt  = (int*)           carve((size_t)nbins * 4);
    float*          dinv    = (float*)         carve((size_t)N * 4);
    unsigned*       recs    = (unsigned*)      carve((size_t)nbins * BIN_CAP * 4);
    unsigned short* sortedG = (unsigned short*)carve((size_t)nbins * BIN_CAP * 2);
    int*            startG  = (int*)           carve((size_t)nbins * 65 * 4);
    __half*         bufG    = (__half*)        carve((size_t)N * 128 * 2);  // g1 gather table
    __half*         bufG2   = (__half*)        carve((size_t)N * 64 * 2);   // g2 gather table

    hipMemsetAsync(binCnt, 0, (size_t)nbins * 4, stream);

    // ---- bin + single sort pass ----
    int numTiles = (E + TILE - 1) / TILE;
    size_t binLds = (size_t)nbins * 2 * 4;
    bin_kernel<<<numTiles, 512, binLds, stream>>>(src, dst, E, nbins, binCnt, recs);
    sort_bins<<<nbins, 512, 0, stream>>>(recs, binCnt, sortedG, startG, dinv, N);

    int gemmGrid = (N + 63) / 64;

    // ---- layer 1 GEMM ----
    gemm_mfma<128, true><<<gemmGrid, 256, 0, stream>>>(x, W1, dinv, bufG, N);

    // ---- fused: layer-1 agg + layer-2 GEMM (h1 stays in LDS) ----
    agg_gemm_fused<<<nbins, 512, 0, stream>>>(bufG, sortedG, startG, dinv, b1, W2, bufG2, N);

    // ---- layer 2 aggregation ----
    dim3 aggGrid(nbins, 2);
    agg_64<<<aggGrid, 512, 0, stream>>>(bufG2, sortedG, startG, dinv, b2, out, N);
}